// Round 15
// baseline (3155.787 us; speedup 1.0000x reference)
//
#include <hip/hip_runtime.h>

// LSTMConditioned: conv-encoder + attention-LSTM (T=64) + MDN head.
// N=128, T=64, HID=512, COMB=1024, ATT=128, K=20, D=2, FMAP=64, L=196, ODIM=121.
// Loop: ONE launch per step (65 total). Cross-block h dependency dissolved by
// REDUNDANT cell recomputation: each block rebuilds the h-slice it needs from
// gpart(t-1) (bf16, MFMA C-fragment layout), z(t-1), c(t-1) (ping-pong buffers).
// k_step (160 blk x 512 thr): blk 0-127 = cell(own sample)+attention(t);
// blk 128-159 = cell(all samples via z-part MFMA)+Whh-GEMM -> gpart(t).

#define TN 128
#define TT 64

typedef __attribute__((ext_vector_type(4))) float f32x4;
typedef __attribute__((ext_vector_type(8))) short bf16x8;

__device__ __forceinline__ float fsigm(float x){ return __builtin_amdgcn_rcpf(1.0f + __expf(-x)); }
__device__ __forceinline__ float ftanh(float x){ return 1.0f - 2.0f*__builtin_amdgcn_rcpf(1.0f + __expf(2.0f*x)); }
__device__ __forceinline__ unsigned short f2bf(float f){
  unsigned int u = __float_as_uint(f);
  u += 0x7fffu + ((u >> 16) & 1u);
  return (unsigned short)(u >> 16);
}
__device__ __forceinline__ float b2f(unsigned short u){ return __uint_as_float(((unsigned)u)<<16); }
__device__ __forceinline__ void cvt8(unsigned short* d, const float* s){
  __align__(16) unsigned short vals[8];
  #pragma unroll
  for (int j=0;j<8;j++) vals[j] = f2bf(s[j]);
  *(float4*)d = *(float4*)vals;
}

// ---------------- device bodies ----------------
__device__ __forceinline__ void dev_conv1(int idx, const float* __restrict__ xc,
    const float* __restrict__ w, const float* __restrict__ b, unsigned short* __restrict__ c1bf){
  if (idx >= TN*16*784) return;
  int p = idx % 784, oc = (idx/784) & 15, n = idx/(784*16);
  int py = p/28, px = p%28;
  const float* src = xc + n*784;
  float acc = b[oc];
  #pragma unroll
  for (int ky=0;ky<3;ky++){
    int iy = py+ky-1; if (iy<0||iy>=28) continue;
    #pragma unroll
    for (int kx=0;kx<3;kx++){
      int ix = px+kx-1; if (ix<0||ix>=28) continue;
      acc += (src[iy*28+ix]-0.0243f)*(1.0f/0.1383f) * w[oc*9+ky*3+kx];
    }
  }
  c1bf[idx] = f2bf(fmaxf(acc, 0.0f));
}

__device__ __forceinline__ void dev_prep(int u,
    const float* __restrict__ Whh, const float* __restrict__ Wih,
    const float* __restrict__ bih, const float* __restrict__ bhh,
    const float* __restrict__ comb_w, const float* __restrict__ out_w, const float* __restrict__ out_b,
    const float* __restrict__ Uw, const float* __restrict__ beta_w, const float* __restrict__ Ww,
    const float* __restrict__ conv2_w, const float* __restrict__ conv3_w,
    unsigned short* __restrict__ wgf, float* __restrict__ gbias,
    unsigned short* __restrict__ cwbf, unsigned short* __restrict__ owbf, float* __restrict__ obias,
    unsigned short* __restrict__ uwbf, unsigned short* __restrict__ betabf, unsigned short* __restrict__ wwbf,
    unsigned short* __restrict__ w2b, unsigned short* __restrict__ w3b){
  if (u < 155648){   // wgf fragment order (units of 8)
    int fragi = u >> 6, lane = u & 63;
    int g = fragi / 608, rem = fragi - g*608;
    int b = rem / 19, kt = rem - b*19;
    int row = g*512 + b*16 + (lane & 15);
    int col = kt*32 + (lane >> 4)*8;
    __align__(16) unsigned short vals[8];
    if (col < 512){
      const float* s = Whh + (size_t)row*512 + col;
      #pragma unroll
      for (int j=0;j<8;j++) vals[j] = f2bf(s[j]);
    } else if (col - 512 < 80){
      const float* s = Wih + (size_t)row*80 + (col-512);
      #pragma unroll
      for (int j=0;j<8;j++) vals[j] = f2bf(s[j]);
    } else {
      #pragma unroll
      for (int j=0;j<8;j++) vals[j] = 0;
    }
    *(float4*)(wgf + (size_t)u*8) = *(float4*)vals;
    return;
  }
  u -= 155648;
  if (u < 256){
    #pragma unroll
    for (int j=0;j<8;j++) gbias[u*8+j] = bih[u*8+j] + bhh[u*8+j];
    return;
  }
  u -= 256;
  if (u < 77824){ cvt8(cwbf + (size_t)u*8, comb_w + (size_t)u*8); return; }
  u -= 77824;
  if (u < 16384){
    int o = u >> 7, k2 = (u & 127)*8;
    __align__(16) unsigned short vals[8];
    if (o < 121){
      const float* s = out_w + (size_t)o*1024 + k2;
      #pragma unroll
      for (int j=0;j<8;j++) vals[j] = f2bf(s[j]);
    } else {
      #pragma unroll
      for (int j=0;j<8;j++) vals[j] = 0;
    }
    *(float4*)(owbf + (size_t)u*8) = *(float4*)vals;
    return;
  }
  u -= 16384;
  if (u < 16){
    #pragma unroll
    for (int j=0;j<8;j++){ int i = u*8+j; obias[i] = (i<121)? out_b[i] : 0.0f; }
    return;
  }
  u -= 16;
  if (u < 8192){ cvt8(uwbf + (size_t)u*8, Uw + (size_t)u*8); return; }
  u -= 8192;
  if (u < 4096){ cvt8(betabf + (size_t)u*8, beta_w + (size_t)u*8); return; }
  u -= 4096;
  if (u < 1024){ cvt8(wwbf + (size_t)u*8, Ww + (size_t)u*8); return; }
  u -= 1024;
  if (u < 640){
    int o = u/20, k2 = (u - o*20)*8;
    if (k2 < 144) cvt8(w2b + (size_t)u*8, conv2_w + (size_t)o*144 + k2);
    else { __align__(16) unsigned short z[8] = {0,0,0,0,0,0,0,0}; *(float4*)(w2b + (size_t)u*8) = *(float4*)z; }
    return;
  }
  u -= 640;
  if (u < 2560){
    int o = u/40, k2 = (u - o*40)*8;
    if (k2 < 288) cvt8(w3b + (size_t)u*8, conv3_w + (size_t)o*288 + k2);
    else { __align__(16) unsigned short z[8] = {0,0,0,0,0,0,0,0}; *(float4*)(w3b + (size_t)u*8) = *(float4*)z; }
    return;
  }
}

// ---------------- head: conv1 || weight prep ----------------
__global__ __launch_bounds__(256) void k_head(const float* __restrict__ xc,
    const float* __restrict__ conv1_w, const float* __restrict__ conv1_b, unsigned short* __restrict__ c1bf,
    const float* __restrict__ Whh, const float* __restrict__ Wih,
    const float* __restrict__ bih, const float* __restrict__ bhh,
    const float* __restrict__ comb_w, const float* __restrict__ out_w, const float* __restrict__ out_b,
    const float* __restrict__ Uw, const float* __restrict__ beta_w, const float* __restrict__ Ww,
    const float* __restrict__ conv2_w, const float* __restrict__ conv3_w,
    unsigned short* __restrict__ wgf, float* __restrict__ gbias,
    unsigned short* __restrict__ cwbf, unsigned short* __restrict__ owbf, float* __restrict__ obias,
    unsigned short* __restrict__ uwbf, unsigned short* __restrict__ betabf, unsigned short* __restrict__ wwbf,
    unsigned short* __restrict__ w2b, unsigned short* __restrict__ w3b){
  int bid = blockIdx.x;
  if (bid < 6272) dev_conv1(bid*256 + threadIdx.x, xc, conv1_w, conv1_b, c1bf);
  else dev_prep((bid-6272)*256 + threadIdx.x, Whh, Wih, bih, bhh, comb_w, out_w, out_b,
                Uw, beta_w, Ww, conv2_w, conv3_w,
                wgf, gbias, cwbf, owbf, obias, uwbf, betabf, wwbf, w2b, w3b);
}

// ---------------- im2col for conv2 ----------------
__global__ __launch_bounds__(256) void k_im2col2(const unsigned short* __restrict__ c1bf, unsigned short* __restrict__ a2){
  int u = blockIdx.x*256 + threadIdx.x;   // 100352*20 units, grid 7840
  if (u >= 100352*20) return;
  int r = u / 20, k8 = (u - r*20)*8;
  int p = r % 784, n = r / 784;
  int py = p/28, px = p%28;
  __align__(16) unsigned short vals[8];
  #pragma unroll
  for (int j=0;j<8;j++){
    int k = k8 + j;
    unsigned short v = 0;
    if (k < 144){
      int ic = k/9, rem = k - ic*9, ky = rem/3, kx = rem - ky*3;
      int iy = py+ky-1, ix = px+kx-1;
      if (iy>=0 && iy<28 && ix>=0 && ix<28) v = c1bf[(n*16+ic)*784 + iy*28+ix];
    }
    vals[j] = v;
  }
  *(float4*)(a2 + (size_t)r*160 + k8) = *(float4*)vals;
}

// ---------------- conv2 GEMM ----------------
__global__ __launch_bounds__(256) void k_gconv2(const unsigned short* __restrict__ a2,
    const unsigned short* __restrict__ w2b, const float* __restrict__ b2,
    unsigned short* __restrict__ c2bf){
  int mbase = blockIdx.x*128;           // 784 blocks
  int tid = threadIdx.x, w = tid>>6, l = tid&63;
  int lr = l&15, lk = (l>>4)*8;
  __shared__ unsigned short at[128*168];
  {
    int row = tid>>1, off = (tid&1)*80;
    const unsigned short* sp = a2 + (size_t)(mbase+row)*160 + off;
    #pragma unroll
    for (int j=0;j<10;j++) *(float4*)&at[row*168 + off + j*8] = *(const float4*)(sp + j*8);
  }
  __syncthreads();
  f32x4 acc[2][2];
  #pragma unroll
  for (int mi=0;mi<2;mi++){ acc[mi][0]=(f32x4){0,0,0,0}; acc[mi][1]=(f32x4){0,0,0,0}; }
  for (int kt=0; kt<5; ++kt){
    bf16x8 b0 = *(const bf16x8*)(w2b + (0*16+lr)*160 + kt*32 + lk);
    bf16x8 b1 = *(const bf16x8*)(w2b + (1*16+lr)*160 + kt*32 + lk);
    #pragma unroll
    for (int mi=0;mi<2;mi++){
      bf16x8 afrag = *(const bf16x8*)&at[((2*w+mi)*16+lr)*168 + kt*32 + lk];
      acc[mi][0] = __builtin_amdgcn_mfma_f32_16x16x32_bf16(afrag, b0, acc[mi][0], 0,0,0);
      acc[mi][1] = __builtin_amdgcn_mfma_f32_16x16x32_bf16(afrag, b1, acc[mi][1], 0,0,0);
    }
  }
  #pragma unroll
  for (int mi=0;mi<2;mi++){
    #pragma unroll
    for (int j=0;j<2;j++){
      int oc = j*16 + lr;
      float bb = b2[oc];
      #pragma unroll
      for (int i=0;i<4;i++){
        int r = mbase + (2*w+mi)*16 + (l>>4)*4 + i;
        c2bf[(size_t)r*32 + oc] = f2bf(fmaxf(acc[mi][j][i] + bb, 0.0f));
      }
    }
  }
}

// ---------------- im2col for conv3 (stride 2) ----------------
__global__ __launch_bounds__(256) void k_im2col3(const unsigned short* __restrict__ c2bf, unsigned short* __restrict__ a3){
  int u = blockIdx.x*256 + threadIdx.x;   // 25088*40 units, grid 3920
  if (u >= 25088*40) return;
  int r = u / 40, k8 = (u - r*40)*8;
  int p = r % 196, n = r / 196;
  int py = p/14, px = p%14;
  __align__(16) unsigned short vals[8];
  #pragma unroll
  for (int j=0;j<8;j++){
    int k = k8 + j;
    unsigned short v = 0;
    if (k < 288){
      int ic = k/9, rem = k - ic*9, ky = rem/3, kx = rem - ky*3;
      int iy = 2*py+ky-1, ix = 2*px+kx-1;
      if (iy>=0 && iy<28 && ix>=0 && ix<28) v = c2bf[(size_t)(n*784 + iy*28+ix)*32 + ic];
    }
    vals[j] = v;
  }
  *(float4*)(a3 + (size_t)r*320 + k8) = *(float4*)vals;
}

// ---------------- conv3 GEMM: afbf[n][f][l] + abf[r][f] ----------------
__global__ __launch_bounds__(256) void k_gconv3(const unsigned short* __restrict__ a3,
    const unsigned short* __restrict__ w3b, const float* __restrict__ b3,
    unsigned short* __restrict__ afbf, unsigned short* __restrict__ abf){
  int mbase = blockIdx.x*128;           // 196 blocks
  int tid = threadIdx.x, w = tid>>6, l = tid&63;
  int lr = l&15, lk = (l>>4)*8;
  __shared__ unsigned short at[128*168];
  f32x4 acc[2][4];
  #pragma unroll
  for (int mi=0;mi<2;mi++)
    #pragma unroll
    for (int j=0;j<4;j++) acc[mi][j]=(f32x4){0,0,0,0};
  for (int kt2=0; kt2<2; ++kt2){
    {
      int row = tid>>1, off = (tid&1)*80;
      const unsigned short* sp = a3 + (size_t)(mbase+row)*320 + kt2*160 + off;
      #pragma unroll
      for (int j=0;j<10;j++) *(float4*)&at[row*168 + off + j*8] = *(const float4*)(sp + j*8);
    }
    __syncthreads();
    for (int kt=0; kt<5; ++kt){
      #pragma unroll
      for (int mi=0;mi<2;mi++){
        bf16x8 afrag = *(const bf16x8*)&at[((2*w+mi)*16+lr)*168 + kt*32 + lk];
        #pragma unroll
        for (int j=0;j<4;j++){
          bf16x8 bf = *(const bf16x8*)(w3b + (size_t)(j*16+lr)*320 + kt2*160 + kt*32 + lk);
          acc[mi][j] = __builtin_amdgcn_mfma_f32_16x16x32_bf16(afrag, bf, acc[mi][j], 0,0,0);
        }
      }
    }
    __syncthreads();
  }
  #pragma unroll
  for (int mi=0;mi<2;mi++){
    #pragma unroll
    for (int j=0;j<4;j++){
      int oc = j*16 + lr;
      float bb = b3[oc];
      #pragma unroll
      for (int i=0;i<4;i++){
        int r = mbase + (2*w+mi)*16 + (l>>4)*4 + i;
        int n = r/196, p = r - n*196;
        float v = ftanh(acc[mi][j][i] + bb);
        unsigned short vb16 = f2bf(v);
        afbf[(size_t)(n*64+oc)*196 + p] = vb16;
        abf[(size_t)r*64 + oc] = vb16;
      }
    }
  }
}

// ---------------- mid: wa || cbf/ubf fill || h/c init (self-contained amean/se) ----------------
__global__ __launch_bounds__(256) void k_mid(
    const unsigned short* __restrict__ afbf,
    const float* __restrict__ start, const float* __restrict__ sw, const float* __restrict__ sb,
    const unsigned short* __restrict__ abf, const unsigned short* __restrict__ wwbf,
    const float* __restrict__ Wb, unsigned short* __restrict__ wabf,
    const float* __restrict__ x, const float* __restrict__ xw, const float* __restrict__ xb,
    unsigned short* __restrict__ cbf, unsigned short* __restrict__ ubf_all,
    const float* __restrict__ init_w, const float* __restrict__ init_b,
    unsigned short* __restrict__ hbf0, float* __restrict__ cbufA)
{
  const int bid = blockIdx.x, tid = threadIdx.x;
  __shared__ __align__(16) unsigned short at[128*40];
  __shared__ float qp[4][64];
  __shared__ float am[64];
  __shared__ float sse[16];
  if (bid < 196){
    int mbase = bid*128;
    int w = tid>>6, l = tid&63;
    int lr = l & 15, lk = (l>>4)*8;
    f32x4 acc[8][2];
    #pragma unroll
    for (int m=0;m<8;m++){ acc[m][0] = (f32x4){0,0,0,0}; acc[m][1] = (f32x4){0,0,0,0}; }
    for (int kt=0; kt<2; ++kt){
      int row = tid>>1, half = (tid&1)*16;
      const unsigned short* sp = abf + (mbase+row)*64 + kt*32 + half;
      *(float4*)&at[row*40 + half]     = *(const float4*)sp;
      *(float4*)&at[row*40 + half + 8] = *(const float4*)(sp + 8);
      __syncthreads();
      bf16x8 b0 = *(const bf16x8*)(wwbf + ((2*w+0)*16 + lr)*64 + kt*32 + lk);
      bf16x8 b1 = *(const bf16x8*)(wwbf + ((2*w+1)*16 + lr)*64 + kt*32 + lk);
      #pragma unroll
      for (int m=0;m<8;m++){
        bf16x8 afrag = *(const bf16x8*)&at[(m*16+lr)*40 + lk];
        acc[m][0] = __builtin_amdgcn_mfma_f32_16x16x32_bf16(afrag, b0, acc[m][0], 0,0,0);
        acc[m][1] = __builtin_amdgcn_mfma_f32_16x16x32_bf16(afrag, b1, acc[m][1], 0,0,0);
      }
      __syncthreads();
    }
    #pragma unroll
    for (int m=0;m<8;m++){
      #pragma unroll
      for (int j=0;j<2;j++){
        int att = (2*w+j)*16 + lr;
        float wb = Wb[att];
        #pragma unroll
        for (int i=0;i<4;i++){
          int arow = mbase + m*16 + (l>>4)*4 + i;
          int n = arow/196, l2 = arow - n*196;
          wabf[((size_t)n*196 + l2)*128 + att] = f2bf(acc[m][j][i] + wb);
        }
      }
    }
    return;
  }
  if (bid < 2244){
    int idx = (bid-196)*256 + tid;
    if (idx >= TN*TT*64) return;
    int j = idx & 63, r = idx >> 6;
    int n = r >> 6, t = r & 63;
    if (j < 16){
      float acc = xb[j];
      if (t > 0){ const float* xp = x + (n*TT + t-1)*2; acc += xp[0]*xw[j*2] + xp[1]*xw[j*2+1]; }
      cbf[(size_t)r*608 + 576 + j] = f2bf(ftanh(acc));
    } else if (j < 32){
      int jj = j-16;
      cbf[(size_t)r*608 + 592 + jj] = f2bf(ftanh(sb[jj] + start[n*2]*sw[jj*2] + start[n*2+1]*sw[jj*2+1]));
    } else if (j < 48){
      int jj = j-32;
      float acc = xb[jj];
      if (t > 0){ const float* xp = x + (n*TT + t-1)*2; acc += xp[0]*xw[jj*2] + xp[1]*xw[jj*2+1]; }
      ubf_all[((size_t)t*TN + n)*96 + jj] = f2bf(ftanh(acc));
    } else {
      ubf_all[((size_t)t*TN + n)*96 + 80 + (j-48)] = 0;
    }
    return;
  }
  // init role: sample n = bid-2244
  {
    const int n = bid - 2244;
    int f = tid & 63, q = tid >> 6;
    const unsigned short* row = afbf + (size_t)(n*64+f)*196 + q*49;
    float s = 0;
    #pragma unroll 7
    for (int l=0;l<49;l++) s += b2f(row[l]);
    qp[q][f] = s;
    __syncthreads();
    if (tid < 64) am[tid] = (qp[0][tid]+qp[1][tid]+qp[2][tid]+qp[3][tid]) * (1.0f/196.0f);
    else if (tid < 80){
      int j = tid-64;
      sse[j] = ftanh(sb[j] + start[n*2]*sw[j*2] + start[n*2+1]*sw[j*2+1]);
    }
    __syncthreads();
    #pragma unroll
    for (int k=0;k<4;k++){
      int o = tid + k*256;
      const float* wr = init_w + (size_t)o*80;
      float acc = init_b[o];
      #pragma unroll 8
      for (int k2=0;k2<64;k2++) acc += am[k2]*wr[k2];
      #pragma unroll
      for (int k2=0;k2<16;k2++) acc += sse[k2]*wr[64+k2];
      float v = ftanh(acc);
      if (o & 1) cbufA[n*512 + (o>>1)] = v;
      else       hbf0[n*512 + (o>>1)] = f2bf(v);
    }
  }
}

// ---------------- fused step: cell-recompute + attention || cell-recompute + Whh-GEMM ----------------
// t in 0..TT. K(t): rebuilds h-state(t) from gpart(t-1)/z(t-1)/c(t-1), writes cbf[t-1] h-slice,
// then attention(t)->z(t) and Whh-GEMM(h(t))->gpart(t). t==0 reads hbf0/cbufA directly.
// t==TT: cell+cbf only.
__global__ __launch_bounds__(512) void k_step(int t,
    const unsigned short* __restrict__ hbf0,
    const float* __restrict__ cbuf_in, float* __restrict__ cbuf_out,
    const unsigned short* __restrict__ gp_in, unsigned short* __restrict__ gp_out,
    const unsigned short* __restrict__ uwbf, const float* __restrict__ Ub,
    const unsigned short* __restrict__ betabf, const float* __restrict__ beta_b,
    const float* __restrict__ vw, const float* __restrict__ vb,
    const unsigned short* __restrict__ wabf, const unsigned short* __restrict__ afbf,
    unsigned short* __restrict__ ubf_all, unsigned short* __restrict__ cbf,
    const unsigned short* __restrict__ wgf, const float* __restrict__ gbias)
{
  const int bid = blockIdx.x, tid = threadIdx.x;
  __shared__ __align__(16) float hs[512];
  __shared__ __align__(16) float Uh[128];
  __shared__ __align__(16) float vws[128];
  __shared__ float bsig[64];
  __shared__ float ew[196];
  __shared__ float red[8];
  __shared__ float up[4][128];
  __shared__ float qp8[8][64];
  __shared__ float ep2[256][2];
  __shared__ unsigned short ush[96];
  __shared__ __align__(16) unsigned short at2[128*516];   // 132 KB h-tile (gates role)

  if (bid < TN){
    // =================== attention role: sample n = bid ===================
    const int n = bid;
    if (tid < 128) vws[tid] = vw[tid];
    const float vb0 = vb[0];
    if (t == 0){
      hs[tid] = b2f(hbf0[n*512 + tid]);
      __syncthreads();
    } else {
      if (tid < 96) ush[tid] = ubf_all[((size_t)(t-1)*TN + n)*96 + tid];
      __syncthreads();
      // cell for h-col = tid: zpart (scalar from fragment-order Wih) + gpart + bias
      const int bb = tid>>4, lr2 = tid&15;
      const int ntile = n>>4, rr = n&15;
      float gate[4];
      #pragma unroll
      for (int g=0; g<4; ++g){
        float acc = 0.f;
        #pragma unroll
        for (int kt=0; kt<3; ++kt){
          const unsigned short* wp = wgf + (size_t)((g*32+bb)*19 + 16 + kt)*512;
          #pragma unroll
          for (int q=0; q<4; ++q){
            bf16x8 wv = *(const bf16x8*)(wp + (lr2 + 16*q)*8);
            const unsigned short* uu = ush + kt*32 + q*8;
            #pragma unroll
            for (int j=0;j<8;j++) acc += b2f(uu[j]) * b2f((unsigned short)wv[j]);
          }
        }
        acc += b2f(gp_in[(size_t)((g*32+bb)*8 + ntile)*256 + ((rr>>2)*16 + lr2)*4 + (rr&3)]);
        gate[g] = acc + gbias[g*512 + tid];
      }
      float c_old = cbuf_in[n*512 + tid];
      float cs = fsigm(gate[1])*c_old + fsigm(gate[0])*ftanh(gate[2]);
      float h  = fsigm(gate[3])*ftanh(cs);
      cbuf_out[n*512 + tid] = cs;
      hs[tid] = h;
      cbf[((size_t)n*TT + (t-1))*608 + tid] = f2bf(h);
      __syncthreads();
    }
    if (t == TT) return;
    // ---- attention(t) on hs ----
    {
      int att = tid & 127, q = tid >> 7;
      const unsigned short* uw = uwbf + (size_t)att*512 + q*128;
      const float* hh = hs + q*128;
      float acc = 0.f;
      #pragma unroll 4
      for (int k=0;k<128;k+=8){
        bf16x8 v = *(const bf16x8*)(uw + k);
        acc += hh[k+0]*b2f(v[0]) + hh[k+1]*b2f(v[1]) + hh[k+2]*b2f(v[2]) + hh[k+3]*b2f(v[3])
             + hh[k+4]*b2f(v[4]) + hh[k+5]*b2f(v[5]) + hh[k+6]*b2f(v[6]) + hh[k+7]*b2f(v[7]);
      }
      up[q][att] = acc;
    }
    {
      int f = tid & 63, q = tid >> 6;
      const unsigned short* bw = betabf + (size_t)f*512 + q*64;
      const float* hh = hs + q*64;
      float acc = 0.f;
      #pragma unroll 4
      for (int k=0;k<64;k+=8){
        bf16x8 v = *(const bf16x8*)(bw + k);
        acc += hh[k+0]*b2f(v[0]) + hh[k+1]*b2f(v[1]) + hh[k+2]*b2f(v[2]) + hh[k+3]*b2f(v[3])
             + hh[k+4]*b2f(v[4]) + hh[k+5]*b2f(v[5]) + hh[k+6]*b2f(v[6]) + hh[k+7]*b2f(v[7]);
      }
      qp8[q][f] = acc;
    }
    __syncthreads();
    if (tid < 128) Uh[tid] = Ub[tid] + up[0][tid]+up[1][tid]+up[2][tid]+up[3][tid];
    else if (tid < 192){
      int f = tid-128;
      bsig[f] = fsigm(beta_b[f] + qp8[0][f]+qp8[1][f]+qp8[2][f]+qp8[3][f]
                                + qp8[4][f]+qp8[5][f]+qp8[6][f]+qp8[7][f]);
    }
    __syncthreads();
    {
      int l = tid >> 1, half = tid & 1;
      float acc = 0.f;
      if (l < 196){
        const unsigned short* wr = wabf + ((size_t)n*196 + l)*128 + half*64;
        const float* uh = Uh + half*64;
        const float* vv = vws + half*64;
        #pragma unroll 2
        for (int k=0;k<64;k+=8){
          bf16x8 wv = *(const bf16x8*)(wr + k);
          acc += vv[k+0]*ftanh(b2f(wv[0]) + uh[k+0]) + vv[k+1]*ftanh(b2f(wv[1]) + uh[k+1])
               + vv[k+2]*ftanh(b2f(wv[2]) + uh[k+2]) + vv[k+3]*ftanh(b2f(wv[3]) + uh[k+3])
               + vv[k+4]*ftanh(b2f(wv[4]) + uh[k+4]) + vv[k+5]*ftanh(b2f(wv[5]) + uh[k+5])
               + vv[k+6]*ftanh(b2f(wv[6]) + uh[k+6]) + vv[k+7]*ftanh(b2f(wv[7]) + uh[k+7]);
        }
      }
      ep2[l][half] = acc;
    }
    __syncthreads();
    float ex = 0.f;
    if (tid < 196) ex = __expf(vb0 + ep2[tid][0] + ep2[tid][1]);
    float ss = ex;
    #pragma unroll
    for (int off=32; off>0; off>>=1) ss += __shfl_xor(ss, off);
    if ((tid&63)==0) red[tid>>6] = ss;
    if (tid<196) ew[tid] = ex;
    __syncthreads();
    float inv = __builtin_amdgcn_rcpf(red[0]+red[1]+red[2]+red[3]+red[4]+red[5]+red[6]+red[7]);
    {
      int f = tid & 63, q = tid >> 6;
      int l0 = q*25, l1 = (l0+25 < 196) ? l0+25 : 196;
      const unsigned short* an = afbf + (size_t)n*12544 + (size_t)f*196;
      float acc = 0.f;
      for (int l2=l0; l2<l1; l2++) acc += ew[l2]*b2f(an[l2]);
      qp8[q][f] = acc;
    }
    __syncthreads();
    if (tid < 64){
      float z = bsig[tid]*(qp8[0][tid]+qp8[1][tid]+qp8[2][tid]+qp8[3][tid]
                          +qp8[4][tid]+qp8[5][tid]+qp8[6][tid]+qp8[7][tid])*inv;
      unsigned short zb = f2bf(z);
      ubf_all[((size_t)t*TN + n)*96 + 16 + tid] = zb;
      cbf[((size_t)n*TT + t)*608 + 512 + tid] = zb;
    }
  } else {
    // =================== gates role: col-slice b ===================
    if (t == TT) return;
    const int b = bid - TN;
    const int w = tid>>6, l = tid&63, lr = l&15, li = l>>4, lk = li*8;
    const int g = w & 3, mh = w >> 2;
    bf16x8 wreg[16];
    {
      const unsigned short* wp = wgf + ((size_t)(g*32 + b)*19)*512 + (size_t)l*8;
      #pragma unroll
      for (int i=0;i<16;i++) wreg[i] = *(const bf16x8*)(wp + (size_t)i*512);
    }
    if (t == 0){
      for (int i = tid; i < 8192; i += 512){
        int row = i >> 6, seg = (i & 63)*8;
        *(float4*)&at2[row*516 + seg] = *(const float4*)(hbf0 + (size_t)row*512 + seg);
      }
      __syncthreads();
    } else {
      // reconstruct h for ntile = w (16 samples) via z-part MFMA + gpart + cell
      const unsigned short* ub = ubf_all + (size_t)(t-1)*TN*96;
      bf16x8 uf[3];
      #pragma unroll
      for (int kt=0;kt<3;kt++) uf[kt] = *(const bf16x8*)(ub + (size_t)(w*16 + lr)*96 + kt*32 + lk);
      for (int hc=0; hc<32; ++hc){
        f32x4 gg4[4];
        #pragma unroll
        for (int gg=0; gg<4; ++gg){
          f32x4 acc = (f32x4){0,0,0,0};
          #pragma unroll
          for (int kt=0;kt<3;kt++){
            bf16x8 wzf = *(const bf16x8*)(wgf + (size_t)((gg*32+hc)*19 + 16 + kt)*512 + (size_t)l*8);
            acc = __builtin_amdgcn_mfma_f32_16x16x32_bf16(uf[kt], wzf, acc, 0,0,0);
          }
          ushort4 gp4 = *(const ushort4*)(gp_in + (size_t)((gg*32+hc)*8 + w)*256 + l*4);
          float gb = gbias[gg*512 + hc*16 + lr];
          acc[0] += b2f(gp4.x) + gb;
          acc[1] += b2f(gp4.y) + gb;
          acc[2] += b2f(gp4.z) + gb;
          acc[3] += b2f(gp4.w) + gb;
          gg4[gg] = acc;
        }
        #pragma unroll
        for (int i=0;i<4;i++){
          int smp = w*16 + li*4 + i;
          int hcol = hc*16 + lr;
          float c_old = cbuf_in[smp*512 + hcol];
          float cs = fsigm(gg4[1][i])*c_old + fsigm(gg4[0][i])*ftanh(gg4[2][i]);
          float h  = fsigm(gg4[3][i])*ftanh(cs);
          at2[smp*516 + hcol] = f2bf(h);
        }
      }
      __syncthreads();
    }
    // Whh GEMM -> gpart(t), bf16 C-frag layout: frag (g*32+b)*8+ntile, lane l elems l*4..+4
    f32x4 acc[4];
    #pragma unroll
    for (int m2=0;m2<4;m2++) acc[m2] = (f32x4){0,0,0,0};
    #pragma unroll 4
    for (int kt=0; kt<16; ++kt){
      #pragma unroll
      for (int m2=0;m2<4;m2++){
        bf16x8 a = *(const bf16x8*)&at2[((mh*4+m2)*16 + lr)*516 + kt*32 + lk];
        acc[m2] = __builtin_amdgcn_mfma_f32_16x16x32_bf16(a, wreg[kt], acc[m2], 0,0,0);
      }
    }
    #pragma unroll
    for (int m2=0;m2<4;m2++){
      ushort4 st;
      st.x = f2bf(acc[m2][0]); st.y = f2bf(acc[m2][1]);
      st.z = f2bf(acc[m2][2]); st.w = f2bf(acc[m2][3]);
      *(ushort4*)(gp_out + (size_t)((g*32 + b)*8 + (mh*4+m2))*256 + l*4) = st;
    }
  }
}

// ---------------- comb GEMM ----------------
__global__ __launch_bounds__(256) void k_comb(const unsigned short* __restrict__ cbf,
    const unsigned short* __restrict__ cwbf, const float* __restrict__ comb_b,
    unsigned short* __restrict__ ybf){
  int mbase = blockIdx.x*128, obase = blockIdx.y*128;
  int tid = threadIdx.x, w = tid>>6, l = tid&63;
  int lr = l&15, lk = (l>>4)*8;
  __shared__ unsigned short at[128*40];
  f32x4 acc[8][2];
  #pragma unroll
  for (int m=0;m<8;m++){ acc[m][0] = (f32x4){0,0,0,0}; acc[m][1] = (f32x4){0,0,0,0}; }
  for (int kt=0; kt<19; ++kt){
    int row = tid>>1, half = (tid&1)*16;
    const unsigned short* sp = cbf + (size_t)(mbase+row)*608 + kt*32 + half;
    *(float4*)&at[row*40 + half]     = *(const float4*)sp;
    *(float4*)&at[row*40 + half + 8] = *(const float4*)(sp + 8);
    __syncthreads();
    bf16x8 b0 = *(const bf16x8*)(cwbf + (size_t)(obase + (2*w+0)*16 + lr)*608 + kt*32 + lk);
    bf16x8 b1 = *(const bf16x8*)(cwbf + (size_t)(obase + (2*w+1)*16 + lr)*608 + kt*32 + lk);
    #pragma unroll
    for (int m=0;m<8;m++){
      bf16x8 afrag = *(const bf16x8*)&at[(m*16+lr)*40 + lk];
      acc[m][0] = __builtin_amdgcn_mfma_f32_16x16x32_bf16(afrag, b0, acc[m][0], 0,0,0);
      acc[m][1] = __builtin_amdgcn_mfma_f32_16x16x32_bf16(afrag, b1, acc[m][1], 0,0,0);
    }
    __syncthreads();
  }
  #pragma unroll
  for (int m=0;m<8;m++){
    #pragma unroll
    for (int j=0;j<2;j++){
      int o = obase + (2*w+j)*16 + lr;
      float cb = comb_b[o];
      #pragma unroll
      for (int i=0;i<4;i++){
        int r = mbase + m*16 + (l>>4)*4 + i;
        ybf[(size_t)r*1024 + o] = f2bf(ftanh(acc[m][j][i] + cb));
      }
    }
  }
}

// ---------------- out GEMM + fused postprocess ----------------
__global__ __launch_bounds__(256) void k_out(const unsigned short* __restrict__ ybf,
    const unsigned short* __restrict__ owbf, const float* __restrict__ obias,
    float* __restrict__ out){
  int mbase = blockIdx.x*128;
  int tid = threadIdx.x, w = tid>>6, l = tid&63;
  int lr = l&15, lk = (l>>4)*8;
  __shared__ unsigned short at[128*40];
  __shared__ float osh[128][129];
  f32x4 acc[8][2];
  #pragma unroll
  for (int m=0;m<8;m++){ acc[m][0] = (f32x4){0,0,0,0}; acc[m][1] = (f32x4){0,0,0,0}; }
  for (int kt=0; kt<32; ++kt){
    int row = tid>>1, half = (tid&1)*16;
    const unsigned short* sp = ybf + (size_t)(mbase+row)*1024 + kt*32 + half;
    *(float4*)&at[row*40 + half]     = *(const float4*)sp;
    *(float4*)&at[row*40 + half + 8] = *(const float4*)(sp + 8);
    __syncthreads();
    bf16x8 b0 = *(const bf16x8*)(owbf + ((2*w+0)*16 + lr)*1024 + kt*32 + lk);
    bf16x8 b1 = *(const bf16x8*)(owbf + ((2*w+1)*16 + lr)*1024 + kt*32 + lk);
    #pragma unroll
    for (int m=0;m<8;m++){
      bf16x8 afrag = *(const bf16x8*)&at[(m*16+lr)*40 + lk];
      acc[m][0] = __builtin_amdgcn_mfma_f32_16x16x32_bf16(afrag, b0, acc[m][0], 0,0,0);
      acc[m][1] = __builtin_amdgcn_mfma_f32_16x16x32_bf16(afrag, b1, acc[m][1], 0,0,0);
    }
    __syncthreads();
  }
  #pragma unroll
  for (int m=0;m<8;m++){
    #pragma unroll
    for (int j=0;j<2;j++){
      int o = (2*w+j)*16 + lr;
      float ob = obias[o];
      #pragma unroll
      for (int i=0;i<4;i++){
        int r = m*16 + (l>>4)*4 + i;
        osh[r][o] = acc[m][j][i] + ob;
      }
    }
  }
  __syncthreads();
  if (tid < 128){
    const float* row = osh[tid];
    int r = mbase + tid;
    float mx = -1e30f;
    #pragma unroll
    for (int k2=0;k2<20;k2++) mx = fmaxf(mx, row[k2]);
    float e[20]; float s = 0;
    #pragma unroll
    for (int k2=0;k2<20;k2++){ e[k2] = __expf(row[k2]-mx); s += e[k2]; }
    float inv = __builtin_amdgcn_rcpf(s);
    float* mixo  = out;
    float* meano = out + 163840;
    float* scaleo= out + 491520;
    float* corro = out + 819200;
    float* vlogo = out + 983040;
    #pragma unroll
    for (int k2=0;k2<20;k2++) mixo[r*20+k2] = e[k2]*inv;
    #pragma unroll
    for (int j=0;j<40;j++) meano[r*40+j] = row[20+j];
    #pragma unroll
    for (int j=0;j<40;j++) scaleo[r*40+j] = __expf(row[60+j]);
    #pragma unroll
    for (int k2=0;k2<20;k2++) corro[r*20+k2] = ftanh(row[100+k2]);
    vlogo[r] = row[120];
  }
}

extern "C" void kernel_launch(void* const* d_in, const int* in_sizes, int n_in,
                              void* d_out, int out_size, void* d_ws, size_t ws_size,
                              hipStream_t stream){
  const float* x       = (const float*)d_in[0];
  const float* x_canv  = (const float*)d_in[1];
  const float* start_  = (const float*)d_in[2];
  const float* conv1_w = (const float*)d_in[3];
  const float* conv1_b = (const float*)d_in[4];
  const float* conv2_w = (const float*)d_in[5];
  const float* conv2_b = (const float*)d_in[6];
  const float* conv3_w = (const float*)d_in[7];
  const float* conv3_b = (const float*)d_in[8];
  const float* init_w  = (const float*)d_in[9];
  const float* init_b  = (const float*)d_in[10];
  const float* Uw      = (const float*)d_in[11];
  const float* Ub      = (const float*)d_in[12];
  const float* Ww      = (const float*)d_in[13];
  const float* Wb      = (const float*)d_in[14];
  const float* vw      = (const float*)d_in[15];
  const float* vb      = (const float*)d_in[16];
  const float* beta_w  = (const float*)d_in[17];
  const float* beta_b  = (const float*)d_in[18];
  const float* xemb_w  = (const float*)d_in[19];
  const float* xemb_b  = (const float*)d_in[20];
  const float* semb_w  = (const float*)d_in[21];
  const float* semb_b  = (const float*)d_in[22];
  const float* Wih     = (const float*)d_in[23];
  const float* Whh     = (const float*)d_in[24];
  const float* bih     = (const float*)d_in[25];
  const float* bhh     = (const float*)d_in[26];
  const float* comb_w  = (const float*)d_in[27];
  const float* comb_b  = (const float*)d_in[28];
  const float* out_w   = (const float*)d_in[29];
  const float* out_b   = (const float*)d_in[30];
  (void)in_sizes; (void)n_in; (void)out_size; (void)ws_size;

  char* wsb = (char*)d_ws;
  size_t off = 0;
  auto alloc = [&](size_t bytes)->char*{
    char* p = wsb + off;
    off = (off + bytes + 255) & ~(size_t)255;
    return p;
  };
  unsigned short* c1bf   = (unsigned short*)alloc((size_t)TN*16*784*2);
  unsigned short* a2     = (unsigned short*)alloc((size_t)100352*160*2);  // a3 aliases a2
  unsigned short* a3     = a2;
  unsigned short* c2bf   = (unsigned short*)alloc((size_t)100352*32*2);
  unsigned short* afbf   = (unsigned short*)alloc((size_t)TN*64*196*2);
  unsigned short* abf    = (unsigned short*)alloc((size_t)TN*196*64*2);
  unsigned short* wabf   = (unsigned short*)alloc((size_t)TN*196*128*2);
  float*          cbufA  = (float*)alloc((size_t)TN*512*4);
  float*          cbufB  = (float*)alloc((size_t)TN*512*4);
  unsigned short* hbf0   = (unsigned short*)alloc((size_t)TN*512*2);
  unsigned short* ubf_all= (unsigned short*)alloc((size_t)TT*TN*96*2);
  unsigned short* cbf    = (unsigned short*)alloc((size_t)TN*TT*608*2);
  unsigned short* ybf    = (unsigned short*)alloc((size_t)TN*TT*1024*2);
  unsigned short* wgf    = (unsigned short*)alloc((size_t)1245184*2);
  float*          gbias  = (float*)alloc((size_t)2048*4);
  unsigned short* gpA    = (unsigned short*)alloc((size_t)262144*2);
  unsigned short* gpB    = (unsigned short*)alloc((size_t)262144*2);
  unsigned short* cwbf   = (unsigned short*)alloc((size_t)1024*608*2);
  unsigned short* owbf   = (unsigned short*)alloc((size_t)128*1024*2);
  float*          obias  = (float*)alloc((size_t)128*4);
  unsigned short* uwbf   = (unsigned short*)alloc((size_t)128*512*2);
  unsigned short* betabf = (unsigned short*)alloc((size_t)64*512*2);
  unsigned short* wwbf   = (unsigned short*)alloc((size_t)128*64*2);
  unsigned short* w2b    = (unsigned short*)alloc((size_t)32*160*2);
  unsigned short* w3b    = (unsigned short*)alloc((size_t)64*320*2);

  hipLaunchKernelGGL(k_head, dim3(7314), dim3(256), 0, stream,
                     x_canv, conv1_w, conv1_b, c1bf,
                     Whh, Wih, bih, bhh, comb_w, out_w, out_b, Uw, beta_w, Ww, conv2_w, conv3_w,
                     wgf, gbias, cwbf, owbf, obias, uwbf, betabf, wwbf, w2b, w3b);
  hipLaunchKernelGGL(k_im2col2, dim3(7840), dim3(256), 0, stream, c1bf, a2);
  hipLaunchKernelGGL(k_gconv2, dim3(784), dim3(256), 0, stream, a2, w2b, conv2_b, c2bf);
  hipLaunchKernelGGL(k_im2col3, dim3(3920), dim3(256), 0, stream, c2bf, a3);
  hipLaunchKernelGGL(k_gconv3, dim3(196), dim3(256), 0, stream, a3, w3b, conv3_b, afbf, abf);
  hipLaunchKernelGGL(k_mid, dim3(2372), dim3(256), 0, stream,
                     afbf, start_, semb_w, semb_b,
                     abf, wwbf, Wb, wabf,
                     x, xemb_w, xemb_b, cbf, ubf_all,
                     init_w, init_b, hbf0, cbufA);

  for (int t = 0; t <= TT; ++t){
    const unsigned short* gp_in = ((t+1)&1) ? gpB : gpA;   // K(t) reads gpart(t-1)
    unsigned short*       gp_out = (t&1) ? gpB : gpA;       // K(t) writes gpart(t)
    const float* c_in  = (t&1) ? cbufA : cbufB;
    float*       c_out = (t&1) ? cbufB : cbufA;
    hipLaunchKernelGGL(k_step, dim3(160), dim3(512), 0, stream, t,
                       hbf0, c_in, c_out, gp_in, gp_out,
                       uwbf, Ub, betabf, beta_b, vw, vb, wabf, afbf,
                       ubf_all, cbf, wgf, gbias);
  }

  hipLaunchKernelGGL(k_comb, dim3(64, 8), dim3(256), 0, stream, cbf, cwbf, comb_b, ybf);
  hipLaunchKernelGGL(k_out, dim3(64), dim3(256), 0, stream, ybf, owbf, obias, (float*)d_out);
}

// Round 16
// 1462.892 us; speedup vs baseline: 2.1572x; 2.1572x over previous
//
#include <hip/hip_runtime.h>

// LSTMConditioned: conv-encoder + attention-LSTM (T=64) + MDN head.
// N=128, T=64, HID=512, COMB=1024, ATT=128, K=20, D=2, FMAP=64, L=196, ODIM=121.
// Loop: 2 launches/step (launch-boundary sync is the only cheap sync on MI355X;
// in-kernel cross-block sync measured 44-183us/step; zero-sync / redundant-recompute
// variants measured latency-bound at 50-180us/step). This is the measured-best structure.
// stepA (160 blk x 512thr) = attention (blk 0-127) || gates Whh-GEMM (blk 128-159).
// stepB (32 blk x 512thr) = z-part GEMM + fused cell update (gpart in [g][b][n][16]
// layout so stepB reads are fully contiguous).

#define TN 128
#define TT 64

typedef __attribute__((ext_vector_type(4))) float f32x4;
typedef __attribute__((ext_vector_type(8))) short bf16x8;

__device__ __forceinline__ float fsigm(float x){ return __builtin_amdgcn_rcpf(1.0f + __expf(-x)); }
__device__ __forceinline__ float ftanh(float x){ return 1.0f - 2.0f*__builtin_amdgcn_rcpf(1.0f + __expf(2.0f*x)); }
__device__ __forceinline__ unsigned short f2bf(float f){
  unsigned int u = __float_as_uint(f);
  u += 0x7fffu + ((u >> 16) & 1u);
  return (unsigned short)(u >> 16);
}
__device__ __forceinline__ float b2f(unsigned short u){ return __uint_as_float(((unsigned)u)<<16); }
__device__ __forceinline__ void cvt8(unsigned short* d, const float* s){
  __align__(16) unsigned short vals[8];
  #pragma unroll
  for (int j=0;j<8;j++) vals[j] = f2bf(s[j]);
  *(float4*)d = *(float4*)vals;
}

// ---------------- device bodies ----------------
__device__ __forceinline__ void dev_conv1(int idx, const float* __restrict__ xc,
    const float* __restrict__ w, const float* __restrict__ b, unsigned short* __restrict__ c1bf){
  if (idx >= TN*16*784) return;
  int p = idx % 784, oc = (idx/784) & 15, n = idx/(784*16);
  int py = p/28, px = p%28;
  const float* src = xc + n*784;
  float acc = b[oc];
  #pragma unroll
  for (int ky=0;ky<3;ky++){
    int iy = py+ky-1; if (iy<0||iy>=28) continue;
    #pragma unroll
    for (int kx=0;kx<3;kx++){
      int ix = px+kx-1; if (ix<0||ix>=28) continue;
      acc += (src[iy*28+ix]-0.0243f)*(1.0f/0.1383f) * w[oc*9+ky*3+kx];
    }
  }
  c1bf[idx] = f2bf(fmaxf(acc, 0.0f));
}

__device__ __forceinline__ void dev_prep(int u,
    const float* __restrict__ Whh, const float* __restrict__ Wih,
    const float* __restrict__ bih, const float* __restrict__ bhh,
    const float* __restrict__ comb_w, const float* __restrict__ out_w, const float* __restrict__ out_b,
    const float* __restrict__ Uw, const float* __restrict__ beta_w, const float* __restrict__ Ww,
    const float* __restrict__ conv2_w, const float* __restrict__ conv3_w,
    unsigned short* __restrict__ wgf, float* __restrict__ gbias,
    unsigned short* __restrict__ cwbf, unsigned short* __restrict__ owbf, float* __restrict__ obias,
    unsigned short* __restrict__ uwbf, unsigned short* __restrict__ betabf, unsigned short* __restrict__ wwbf,
    unsigned short* __restrict__ w2b, unsigned short* __restrict__ w3b){
  if (u < 155648){   // wgf fragment order (units of 8)
    int fragi = u >> 6, lane = u & 63;
    int g = fragi / 608, rem = fragi - g*608;
    int b = rem / 19, kt = rem - b*19;
    int row = g*512 + b*16 + (lane & 15);
    int col = kt*32 + (lane >> 4)*8;
    __align__(16) unsigned short vals[8];
    if (col < 512){
      const float* s = Whh + (size_t)row*512 + col;
      #pragma unroll
      for (int j=0;j<8;j++) vals[j] = f2bf(s[j]);
    } else if (col - 512 < 80){
      const float* s = Wih + (size_t)row*80 + (col-512);
      #pragma unroll
      for (int j=0;j<8;j++) vals[j] = f2bf(s[j]);
    } else {
      #pragma unroll
      for (int j=0;j<8;j++) vals[j] = 0;
    }
    *(float4*)(wgf + (size_t)u*8) = *(float4*)vals;
    return;
  }
  u -= 155648;
  if (u < 256){
    #pragma unroll
    for (int j=0;j<8;j++) gbias[u*8+j] = bih[u*8+j] + bhh[u*8+j];
    return;
  }
  u -= 256;
  if (u < 77824){ cvt8(cwbf + (size_t)u*8, comb_w + (size_t)u*8); return; }
  u -= 77824;
  if (u < 16384){
    int o = u >> 7, k2 = (u & 127)*8;
    __align__(16) unsigned short vals[8];
    if (o < 121){
      const float* s = out_w + (size_t)o*1024 + k2;
      #pragma unroll
      for (int j=0;j<8;j++) vals[j] = f2bf(s[j]);
    } else {
      #pragma unroll
      for (int j=0;j<8;j++) vals[j] = 0;
    }
    *(float4*)(owbf + (size_t)u*8) = *(float4*)vals;
    return;
  }
  u -= 16384;
  if (u < 16){
    #pragma unroll
    for (int j=0;j<8;j++){ int i = u*8+j; obias[i] = (i<121)? out_b[i] : 0.0f; }
    return;
  }
  u -= 16;
  if (u < 8192){ cvt8(uwbf + (size_t)u*8, Uw + (size_t)u*8); return; }
  u -= 8192;
  if (u < 4096){ cvt8(betabf + (size_t)u*8, beta_w + (size_t)u*8); return; }
  u -= 4096;
  if (u < 1024){ cvt8(wwbf + (size_t)u*8, Ww + (size_t)u*8); return; }
  u -= 1024;
  if (u < 640){
    int o = u/20, k2 = (u - o*20)*8;
    if (k2 < 144) cvt8(w2b + (size_t)u*8, conv2_w + (size_t)o*144 + k2);
    else { __align__(16) unsigned short z[8] = {0,0,0,0,0,0,0,0}; *(float4*)(w2b + (size_t)u*8) = *(float4*)z; }
    return;
  }
  u -= 640;
  if (u < 2560){
    int o = u/40, k2 = (u - o*40)*8;
    if (k2 < 288) cvt8(w3b + (size_t)u*8, conv3_w + (size_t)o*288 + k2);
    else { __align__(16) unsigned short z[8] = {0,0,0,0,0,0,0,0}; *(float4*)(w3b + (size_t)u*8) = *(float4*)z; }
    return;
  }
}

// ---------------- head: conv1 || weight prep ----------------
__global__ __launch_bounds__(256) void k_head(const float* __restrict__ xc,
    const float* __restrict__ conv1_w, const float* __restrict__ conv1_b, unsigned short* __restrict__ c1bf,
    const float* __restrict__ Whh, const float* __restrict__ Wih,
    const float* __restrict__ bih, const float* __restrict__ bhh,
    const float* __restrict__ comb_w, const float* __restrict__ out_w, const float* __restrict__ out_b,
    const float* __restrict__ Uw, const float* __restrict__ beta_w, const float* __restrict__ Ww,
    const float* __restrict__ conv2_w, const float* __restrict__ conv3_w,
    unsigned short* __restrict__ wgf, float* __restrict__ gbias,
    unsigned short* __restrict__ cwbf, unsigned short* __restrict__ owbf, float* __restrict__ obias,
    unsigned short* __restrict__ uwbf, unsigned short* __restrict__ betabf, unsigned short* __restrict__ wwbf,
    unsigned short* __restrict__ w2b, unsigned short* __restrict__ w3b){
  int bid = blockIdx.x;
  if (bid < 6272) dev_conv1(bid*256 + threadIdx.x, xc, conv1_w, conv1_b, c1bf);
  else dev_prep((bid-6272)*256 + threadIdx.x, Whh, Wih, bih, bhh, comb_w, out_w, out_b,
                Uw, beta_w, Ww, conv2_w, conv3_w,
                wgf, gbias, cwbf, owbf, obias, uwbf, betabf, wwbf, w2b, w3b);
}

// ---------------- im2col for conv2 ----------------
__global__ __launch_bounds__(256) void k_im2col2(const unsigned short* __restrict__ c1bf, unsigned short* __restrict__ a2){
  int u = blockIdx.x*256 + threadIdx.x;   // 100352*20 units, grid 7840
  if (u >= 100352*20) return;
  int r = u / 20, k8 = (u - r*20)*8;
  int p = r % 784, n = r / 784;
  int py = p/28, px = p%28;
  __align__(16) unsigned short vals[8];
  #pragma unroll
  for (int j=0;j<8;j++){
    int k = k8 + j;
    unsigned short v = 0;
    if (k < 144){
      int ic = k/9, rem = k - ic*9, ky = rem/3, kx = rem - ky*3;
      int iy = py+ky-1, ix = px+kx-1;
      if (iy>=0 && iy<28 && ix>=0 && ix<28) v = c1bf[(n*16+ic)*784 + iy*28+ix];
    }
    vals[j] = v;
  }
  *(float4*)(a2 + (size_t)r*160 + k8) = *(float4*)vals;
}

// ---------------- conv2 GEMM ----------------
__global__ __launch_bounds__(256) void k_gconv2(const unsigned short* __restrict__ a2,
    const unsigned short* __restrict__ w2b, const float* __restrict__ b2,
    unsigned short* __restrict__ c2bf){
  int mbase = blockIdx.x*128;           // 784 blocks
  int tid = threadIdx.x, w = tid>>6, l = tid&63;
  int lr = l&15, lk = (l>>4)*8;
  __shared__ unsigned short at[128*168];
  {
    int row = tid>>1, off = (tid&1)*80;
    const unsigned short* sp = a2 + (size_t)(mbase+row)*160 + off;
    #pragma unroll
    for (int j=0;j<10;j++) *(float4*)&at[row*168 + off + j*8] = *(const float4*)(sp + j*8);
  }
  __syncthreads();
  f32x4 acc[2][2];
  #pragma unroll
  for (int mi=0;mi<2;mi++){ acc[mi][0]=(f32x4){0,0,0,0}; acc[mi][1]=(f32x4){0,0,0,0}; }
  for (int kt=0; kt<5; ++kt){
    bf16x8 b0 = *(const bf16x8*)(w2b + (0*16+lr)*160 + kt*32 + lk);
    bf16x8 b1 = *(const bf16x8*)(w2b + (1*16+lr)*160 + kt*32 + lk);
    #pragma unroll
    for (int mi=0;mi<2;mi++){
      bf16x8 afrag = *(const bf16x8*)&at[((2*w+mi)*16+lr)*168 + kt*32 + lk];
      acc[mi][0] = __builtin_amdgcn_mfma_f32_16x16x32_bf16(afrag, b0, acc[mi][0], 0,0,0);
      acc[mi][1] = __builtin_amdgcn_mfma_f32_16x16x32_bf16(afrag, b1, acc[mi][1], 0,0,0);
    }
  }
  #pragma unroll
  for (int mi=0;mi<2;mi++){
    #pragma unroll
    for (int j=0;j<2;j++){
      int oc = j*16 + lr;
      float bb = b2[oc];
      #pragma unroll
      for (int i=0;i<4;i++){
        int r = mbase + (2*w+mi)*16 + (l>>4)*4 + i;
        c2bf[(size_t)r*32 + oc] = f2bf(fmaxf(acc[mi][j][i] + bb, 0.0f));
      }
    }
  }
}

// ---------------- im2col for conv3 (stride 2) ----------------
__global__ __launch_bounds__(256) void k_im2col3(const unsigned short* __restrict__ c2bf, unsigned short* __restrict__ a3){
  int u = blockIdx.x*256 + threadIdx.x;   // 25088*40 units, grid 3920
  if (u >= 25088*40) return;
  int r = u / 40, k8 = (u - r*40)*8;
  int p = r % 196, n = r / 196;
  int py = p/14, px = p%14;
  __align__(16) unsigned short vals[8];
  #pragma unroll
  for (int j=0;j<8;j++){
    int k = k8 + j;
    unsigned short v = 0;
    if (k < 288){
      int ic = k/9, rem = k - ic*9, ky = rem/3, kx = rem - ky*3;
      int iy = 2*py+ky-1, ix = 2*px+kx-1;
      if (iy>=0 && iy<28 && ix>=0 && ix<28) v = c2bf[(size_t)(n*784 + iy*28+ix)*32 + ic];
    }
    vals[j] = v;
  }
  *(float4*)(a3 + (size_t)r*320 + k8) = *(float4*)vals;
}

// ---------------- conv3 GEMM: afbf[n][f][l] + abf[r][f] ----------------
__global__ __launch_bounds__(256) void k_gconv3(const unsigned short* __restrict__ a3,
    const unsigned short* __restrict__ w3b, const float* __restrict__ b3,
    unsigned short* __restrict__ afbf, unsigned short* __restrict__ abf){
  int mbase = blockIdx.x*128;           // 196 blocks
  int tid = threadIdx.x, w = tid>>6, l = tid&63;
  int lr = l&15, lk = (l>>4)*8;
  __shared__ unsigned short at[128*168];
  f32x4 acc[2][4];
  #pragma unroll
  for (int mi=0;mi<2;mi++)
    #pragma unroll
    for (int j=0;j<4;j++) acc[mi][j]=(f32x4){0,0,0,0};
  for (int kt2=0; kt2<2; ++kt2){
    {
      int row = tid>>1, off = (tid&1)*80;
      const unsigned short* sp = a3 + (size_t)(mbase+row)*320 + kt2*160 + off;
      #pragma unroll
      for (int j=0;j<10;j++) *(float4*)&at[row*168 + off + j*8] = *(const float4*)(sp + j*8);
    }
    __syncthreads();
    for (int kt=0; kt<5; ++kt){
      #pragma unroll
      for (int mi=0;mi<2;mi++){
        bf16x8 afrag = *(const bf16x8*)&at[((2*w+mi)*16+lr)*168 + kt*32 + lk];
        #pragma unroll
        for (int j=0;j<4;j++){
          bf16x8 bf = *(const bf16x8*)(w3b + (size_t)(j*16+lr)*320 + kt2*160 + kt*32 + lk);
          acc[mi][j] = __builtin_amdgcn_mfma_f32_16x16x32_bf16(afrag, bf, acc[mi][j], 0,0,0);
        }
      }
    }
    __syncthreads();
  }
  #pragma unroll
  for (int mi=0;mi<2;mi++){
    #pragma unroll
    for (int j=0;j<4;j++){
      int oc = j*16 + lr;
      float bb = b3[oc];
      #pragma unroll
      for (int i=0;i<4;i++){
        int r = mbase + (2*w+mi)*16 + (l>>4)*4 + i;
        int n = r/196, p = r - n*196;
        float v = ftanh(acc[mi][j][i] + bb);
        unsigned short vb16 = f2bf(v);
        afbf[(size_t)(n*64+oc)*196 + p] = vb16;
        abf[(size_t)r*64 + oc] = vb16;
      }
    }
  }
}

// ---------------- mid: wa || cbf/ubf fill || h/c init (self-contained amean/se) ----------------
__global__ __launch_bounds__(256) void k_mid(
    const unsigned short* __restrict__ afbf,
    const float* __restrict__ start, const float* __restrict__ sw, const float* __restrict__ sb,
    const unsigned short* __restrict__ abf, const unsigned short* __restrict__ wwbf,
    const float* __restrict__ Wb, unsigned short* __restrict__ wabf,
    const float* __restrict__ x, const float* __restrict__ xw, const float* __restrict__ xb,
    unsigned short* __restrict__ cbf, unsigned short* __restrict__ ubf_all,
    const float* __restrict__ init_w, const float* __restrict__ init_b,
    unsigned short* __restrict__ hbfA, float* __restrict__ cbuf)
{
  const int bid = blockIdx.x, tid = threadIdx.x;
  __shared__ __align__(16) unsigned short at[128*40];
  __shared__ float qp[4][64];
  __shared__ float am[64];
  __shared__ float sse[16];
  if (bid < 196){
    // wa GEMM: W_a = a @ Ww.T + Wb, stored bf16 [n][l][att]
    int mbase = bid*128;
    int w = tid>>6, l = tid&63;
    int lr = l & 15, lk = (l>>4)*8;
    f32x4 acc[8][2];
    #pragma unroll
    for (int m=0;m<8;m++){ acc[m][0] = (f32x4){0,0,0,0}; acc[m][1] = (f32x4){0,0,0,0}; }
    for (int kt=0; kt<2; ++kt){
      int row = tid>>1, half = (tid&1)*16;
      const unsigned short* sp = abf + (mbase+row)*64 + kt*32 + half;
      *(float4*)&at[row*40 + half]     = *(const float4*)sp;
      *(float4*)&at[row*40 + half + 8] = *(const float4*)(sp + 8);
      __syncthreads();
      bf16x8 b0 = *(const bf16x8*)(wwbf + ((2*w+0)*16 + lr)*64 + kt*32 + lk);
      bf16x8 b1 = *(const bf16x8*)(wwbf + ((2*w+1)*16 + lr)*64 + kt*32 + lk);
      #pragma unroll
      for (int m=0;m<8;m++){
        bf16x8 afrag = *(const bf16x8*)&at[(m*16+lr)*40 + lk];
        acc[m][0] = __builtin_amdgcn_mfma_f32_16x16x32_bf16(afrag, b0, acc[m][0], 0,0,0);
        acc[m][1] = __builtin_amdgcn_mfma_f32_16x16x32_bf16(afrag, b1, acc[m][1], 0,0,0);
      }
      __syncthreads();
    }
    #pragma unroll
    for (int m=0;m<8;m++){
      #pragma unroll
      for (int j=0;j<2;j++){
        int att = (2*w+j)*16 + lr;
        float wb = Wb[att];
        #pragma unroll
        for (int i=0;i<4;i++){
          int arow = mbase + m*16 + (l>>4)*4 + i;
          int n = arow/196, l2 = arow - n*196;
          wabf[((size_t)n*196 + l2)*128 + att] = f2bf(acc[m][j][i] + wb);
        }
      }
    }
    return;
  }
  if (bid < 2244){
    // cbf/ubf fill with inline embeddings
    int idx = (bid-196)*256 + tid;
    if (idx >= TN*TT*64) return;
    int j = idx & 63, r = idx >> 6;
    int n = r >> 6, t = r & 63;
    if (j < 16){
      float acc = xb[j];
      if (t > 0){ const float* xp = x + (n*TT + t-1)*2; acc += xp[0]*xw[j*2] + xp[1]*xw[j*2+1]; }
      cbf[(size_t)r*608 + 576 + j] = f2bf(ftanh(acc));
    } else if (j < 32){
      int jj = j-16;
      cbf[(size_t)r*608 + 592 + jj] = f2bf(ftanh(sb[jj] + start[n*2]*sw[jj*2] + start[n*2+1]*sw[jj*2+1]));
    } else if (j < 48){
      int jj = j-32;
      float acc = xb[jj];
      if (t > 0){ const float* xp = x + (n*TT + t-1)*2; acc += xp[0]*xw[jj*2] + xp[1]*xw[jj*2+1]; }
      ubf_all[((size_t)t*TN + n)*96 + jj] = f2bf(ftanh(acc));
    } else {
      ubf_all[((size_t)t*TN + n)*96 + 80 + (j-48)] = 0;
    }
    return;
  }
  // init role: sample n = bid-2244; recompute amean/se locally, then 1024 dot-80s
  {
    const int n = bid - 2244;
    int f = tid & 63, q = tid >> 6;
    const unsigned short* row = afbf + (size_t)(n*64+f)*196 + q*49;
    float s = 0;
    #pragma unroll 7
    for (int l=0;l<49;l++) s += b2f(row[l]);
    qp[q][f] = s;
    __syncthreads();
    if (tid < 64) am[tid] = (qp[0][tid]+qp[1][tid]+qp[2][tid]+qp[3][tid]) * (1.0f/196.0f);
    else if (tid < 80){
      int j = tid-64;
      sse[j] = ftanh(sb[j] + start[n*2]*sw[j*2] + start[n*2+1]*sw[j*2+1]);
    }
    __syncthreads();
    #pragma unroll
    for (int k=0;k<4;k++){
      int o = tid + k*256;
      const float* wr = init_w + (size_t)o*80;
      float acc = init_b[o];
      #pragma unroll 8
      for (int k2=0;k2<64;k2++) acc += am[k2]*wr[k2];
      #pragma unroll
      for (int k2=0;k2<16;k2++) acc += sse[k2]*wr[64+k2];
      float v = ftanh(acc);
      if (o & 1) cbuf[n*512 + (o>>1)] = v;
      else       hbfA[n*512 + (o>>1)] = f2bf(v);
    }
  }
}

// ---------------- step A: attention (blocks 0-127) || gates-h GEMM (blocks 128-159) ----------------
__global__ __launch_bounds__(512) void k_stepA(int t,
    const unsigned short* __restrict__ hbf_in,
    const unsigned short* __restrict__ uwbf, const float* __restrict__ Ub,
    const unsigned short* __restrict__ betabf, const float* __restrict__ beta_b,
    const float* __restrict__ vw, const float* __restrict__ vb,
    const unsigned short* __restrict__ wabf, const unsigned short* __restrict__ afbf,
    unsigned short* __restrict__ ubf_all, unsigned short* __restrict__ cbf,
    const unsigned short* __restrict__ wgf, float* __restrict__ gpart)
{
  const int bid = blockIdx.x, tid = threadIdx.x;
  __shared__ __align__(16) float hs[512];
  __shared__ __align__(16) float Uh[128];
  __shared__ __align__(16) float vws[128];
  __shared__ float bsig[64];
  __shared__ float ew[196];
  __shared__ float red[8];
  __shared__ float up[4][128];
  __shared__ float qp8[8][64];
  __shared__ float ep2[256][2];
  __shared__ __align__(16) unsigned short at2[128*516];   // 132 KB: full h-tile (gates role)

  if (bid < TN){
    // =================== attention role: sample n = bid ===================
    const int n = bid;
    hs[tid] = b2f(hbf_in[n*512 + tid]);
    if (tid < 128) vws[tid] = vw[tid];
    const float vb0 = vb[0];
    __syncthreads();
    // Uh partials: (att, k-quarter)
    {
      int att = tid & 127, q = tid >> 7;
      const unsigned short* uw = uwbf + (size_t)att*512 + q*128;
      const float* hh = hs + q*128;
      float acc = 0.f;
      #pragma unroll 4
      for (int k=0;k<128;k+=8){
        bf16x8 v = *(const bf16x8*)(uw + k);
        acc += hh[k+0]*b2f(v[0]) + hh[k+1]*b2f(v[1]) + hh[k+2]*b2f(v[2]) + hh[k+3]*b2f(v[3])
             + hh[k+4]*b2f(v[4]) + hh[k+5]*b2f(v[5]) + hh[k+6]*b2f(v[6]) + hh[k+7]*b2f(v[7]);
      }
      up[q][att] = acc;
    }
    // beta partials: (f, k-eighth)
    {
      int f = tid & 63, q = tid >> 6;
      const unsigned short* bw = betabf + (size_t)f*512 + q*64;
      const float* hh = hs + q*64;
      float acc = 0.f;
      #pragma unroll 4
      for (int k=0;k<64;k+=8){
        bf16x8 v = *(const bf16x8*)(bw + k);
        acc += hh[k+0]*b2f(v[0]) + hh[k+1]*b2f(v[1]) + hh[k+2]*b2f(v[2]) + hh[k+3]*b2f(v[3])
             + hh[k+4]*b2f(v[4]) + hh[k+5]*b2f(v[5]) + hh[k+6]*b2f(v[6]) + hh[k+7]*b2f(v[7]);
      }
      qp8[q][f] = acc;
    }
    __syncthreads();
    if (tid < 128) Uh[tid] = Ub[tid] + up[0][tid]+up[1][tid]+up[2][tid]+up[3][tid];
    else if (tid < 192){
      int f = tid-128;
      bsig[f] = fsigm(beta_b[f] + qp8[0][f]+qp8[1][f]+qp8[2][f]+qp8[3][f]
                                + qp8[4][f]+qp8[5][f]+qp8[6][f]+qp8[7][f]);
    }
    __syncthreads();
    // e partials: (l, att-half)
    {
      int l = tid >> 1, half = tid & 1;
      float acc = 0.f;
      if (l < 196){
        const unsigned short* wr = wabf + ((size_t)n*196 + l)*128 + half*64;
        const float* uh = Uh + half*64;
        const float* vv = vws + half*64;
        #pragma unroll 2
        for (int k=0;k<64;k+=8){
          bf16x8 wv = *(const bf16x8*)(wr + k);
          acc += vv[k+0]*ftanh(b2f(wv[0]) + uh[k+0]) + vv[k+1]*ftanh(b2f(wv[1]) + uh[k+1])
               + vv[k+2]*ftanh(b2f(wv[2]) + uh[k+2]) + vv[k+3]*ftanh(b2f(wv[3]) + uh[k+3])
               + vv[k+4]*ftanh(b2f(wv[4]) + uh[k+4]) + vv[k+5]*ftanh(b2f(wv[5]) + uh[k+5])
               + vv[k+6]*ftanh(b2f(wv[6]) + uh[k+6]) + vv[k+7]*ftanh(b2f(wv[7]) + uh[k+7]);
        }
      }
      ep2[l][half] = acc;
    }
    __syncthreads();
    // softmax WITHOUT max-pass: |e| <= |vb| + sum|vw| ~ 6, exp is fp32-safe
    float ex = 0.f;
    if (tid < 196) ex = __expf(vb0 + ep2[tid][0] + ep2[tid][1]);
    float ss = ex;
    #pragma unroll
    for (int off=32; off>0; off>>=1) ss += __shfl_xor(ss, off);
    if ((tid&63)==0) red[tid>>6] = ss;
    if (tid<196) ew[tid] = ex;
    __syncthreads();
    float inv = __builtin_amdgcn_rcpf(red[0]+red[1]+red[2]+red[3]+red[4]+red[5]+red[6]+red[7]);
    // z partials: (f, l-chunk of 25)
    {
      int f = tid & 63, q = tid >> 6;
      int l0 = q*25, l1 = (l0+25 < 196) ? l0+25 : 196;
      const unsigned short* an = afbf + (size_t)n*12544 + (size_t)f*196;
      float acc = 0.f;
      for (int l2=l0; l2<l1; l2++) acc += ew[l2]*b2f(an[l2]);
      qp8[q][f] = acc;
    }
    __syncthreads();
    if (tid < 64){
      float z = bsig[tid]*(qp8[0][tid]+qp8[1][tid]+qp8[2][tid]+qp8[3][tid]
                          +qp8[4][tid]+qp8[5][tid]+qp8[6][tid]+qp8[7][tid])*inv;
      unsigned short zb = f2bf(z);
      ubf_all[((size_t)t*TN + n)*96 + 16 + tid] = zb;
      cbf[((size_t)n*TT + t)*608 + 512 + tid] = zb;
    }
  } else {
    // =================== gates Whh-part role: col-slice b (full h-tile staged once) ===================
    const int b = bid - TN;                       // 0..31
    const int w = tid>>6, l = tid&63, lr = l&15, li = l>>4, lk = li*8;
    const int g = w & 3, mh = w >> 2;             // wave -> (gate, M-half)
    bf16x8 wreg[16];
    {
      const unsigned short* wp = wgf + ((size_t)(g*32 + b)*19)*512 + (size_t)l*8;
      #pragma unroll
      for (int i=0;i<16;i++) wreg[i] = *(const bf16x8*)(wp + (size_t)i*512);
    }
    for (int i = tid; i < 8192; i += 512){
      int row = i >> 6, seg = (i & 63)*8;
      *(float4*)&at2[row*516 + seg] = *(const float4*)(hbf_in + (size_t)row*512 + seg);
    }
    __syncthreads();
    f32x4 acc[4];
    #pragma unroll
    for (int m2=0;m2<4;m2++) acc[m2] = (f32x4){0,0,0,0};
    #pragma unroll 4
    for (int kt=0; kt<16; ++kt){
      #pragma unroll
      for (int m2=0;m2<4;m2++){
        bf16x8 a = *(const bf16x8*)&at2[((mh*4+m2)*16 + lr)*516 + kt*32 + lk];
        acc[m2] = __builtin_amdgcn_mfma_f32_16x16x32_bf16(a, wreg[kt], acc[m2], 0,0,0);
      }
    }
    // gpart layout [g][b][n][16] -> stepB reads are contiguous
    #pragma unroll
    for (int m2=0;m2<4;m2++){
      #pragma unroll
      for (int i=0;i<4;i++){
        int n2 = (mh*4+m2)*16 + li*4 + i;
        gpart[(((size_t)(g*32 + b)*128 + n2)<<4) + lr] = acc[m2][i];
      }
    }
  }
}

// ---------------- step B: z-part GEMM (direct u-frags) + cell update (32 blocks x 512 thr) ----------------
__global__ __launch_bounds__(512) void k_stepB(int t,
    unsigned short* __restrict__ hout,
    const unsigned short* __restrict__ ubf_all,
    const unsigned short* __restrict__ wgf, const float* __restrict__ gbias,
    const float* __restrict__ gpart,
    float* __restrict__ cbuf, unsigned short* __restrict__ cbf)
{
  const int b = blockIdx.x, tid = threadIdx.x;
  const int w = tid>>6, l = tid&63, lr = l&15, li = l>>4, lk = li*8;
  const int g = w & 3, mh = w >> 2;
  __shared__ float gsh[4][128][16];              // 32 KB: gate accumulators
  const unsigned short* ub = ubf_all + (size_t)t*TN*96;
  bf16x8 wz[3];
  {
    const unsigned short* wp = wgf + (((size_t)(g*32 + b)*19) + 16)*512 + (size_t)l*8;
    #pragma unroll
    for (int i=0;i<3;i++) wz[i] = *(const bf16x8*)(wp + (size_t)i*512);
  }
  // load gpart -> gsh: [g][b][n][16] layout, fully contiguous 8KB per g
  for (int i = tid; i < 2048; i += 512){
    int gg = i>>9, r = i&511;   // r = n*4 + j4
    *(float4*)&gsh[gg][r>>2][(r&3)*4] = *(const float4*)&gpart[(((size_t)(gg*32 + b)*128)<<4) + r*4];
  }
  f32x4 acc[4];
  #pragma unroll
  for (int m2=0;m2<4;m2++) acc[m2] = (f32x4){0,0,0,0};
  #pragma unroll
  for (int kt=0; kt<3; ++kt){
    #pragma unroll
    for (int m2=0;m2<4;m2++){
      bf16x8 a = *(const bf16x8*)(ub + (size_t)((mh*4+m2)*16 + lr)*96 + kt*32 + lk);
      acc[m2] = __builtin_amdgcn_mfma_f32_16x16x32_bf16(a, wz[kt], acc[m2], 0,0,0);
    }
  }
  __syncthreads();   // gsh fully loaded
  #pragma unroll
  for (int m2=0;m2<4;m2++)
    #pragma unroll
    for (int i=0;i<4;i++)
      gsh[g][(mh*4+m2)*16 + li*4 + i][lr] += acc[m2][i];
  __syncthreads();
  #pragma unroll
  for (int e=0;e<4;++e){
    int c = tid*4 + e;
    int nn = c>>4, j = c&15;
    int hidx = b*16 + j;
    float gi = gsh[0][nn][j] + gbias[         hidx];
    float gf = gsh[1][nn][j] + gbias[1*512 + hidx];
    float gg = gsh[2][nn][j] + gbias[2*512 + hidx];
    float go = gsh[3][nn][j] + gbias[3*512 + hidx];
    float cc = cbuf[nn*512 + hidx];
    float cs = fsigm(gf)*cc + fsigm(gi)*ftanh(gg);
    float h  = fsigm(go)*ftanh(cs);
    cbuf[nn*512 + hidx] = cs;
    unsigned short hb = f2bf(h);
    hout[nn*512 + hidx] = hb;
    cbf[((size_t)nn*TT + t)*608 + hidx] = hb;
  }
}

// ---------------- comb GEMM ----------------
__global__ __launch_bounds__(256) void k_comb(const unsigned short* __restrict__ cbf,
    const unsigned short* __restrict__ cwbf, const float* __restrict__ comb_b,
    unsigned short* __restrict__ ybf){
  int mbase = blockIdx.x*128, obase = blockIdx.y*128;
  int tid = threadIdx.x, w = tid>>6, l = tid&63;
  int lr = l&15, lk = (l>>4)*8;
  __shared__ unsigned short at[128*40];
  f32x4 acc[8][2];
  #pragma unroll
  for (int m=0;m<8;m++){ acc[m][0] = (f32x4){0,0,0,0}; acc[m][1] = (f32x4){0,0,0,0}; }
  for (int kt=0; kt<19; ++kt){
    int row = tid>>1, half = (tid&1)*16;
    const unsigned short* sp = cbf + (size_t)(mbase+row)*608 + kt*32 + half;
    *(float4*)&at[row*40 + half]     = *(const float4*)sp;
    *(float4*)&at[row*40 + half + 8] = *(const float4*)(sp + 8);
    __syncthreads();
    bf16x8 b0 = *(const bf16x8*)(cwbf + (size_t)(obase + (2*w+0)*16 + lr)*608 + kt*32 + lk);
    bf16x8 b1 = *(const bf16x8*)(cwbf + (size_t)(obase + (2*w+1)*16 + lr)*608 + kt*32 + lk);
    #pragma unroll
    for (int m=0;m<8;m++){
      bf16x8 afrag = *(const bf16x8*)&at[(m*16+lr)*40 + lk];
      acc[m][0] = __builtin_amdgcn_mfma_f32_16x16x32_bf16(afrag, b0, acc[m][0], 0,0,0);
      acc[m][1] = __builtin_amdgcn_mfma_f32_16x16x32_bf16(afrag, b1, acc[m][1], 0,0,0);
    }
    __syncthreads();
  }
  #pragma unroll
  for (int m=0;m<8;m++){
    #pragma unroll
    for (int j=0;j<2;j++){
      int o = obase + (2*w+j)*16 + lr;
      float cb = comb_b[o];
      #pragma unroll
      for (int i=0;i<4;i++){
        int r = mbase + m*16 + (l>>4)*4 + i;
        ybf[(size_t)r*1024 + o] = f2bf(ftanh(acc[m][j][i] + cb));
      }
    }
  }
}

// ---------------- out GEMM + fused postprocess ----------------
__global__ __launch_bounds__(256) void k_out(const unsigned short* __restrict__ ybf,
    const unsigned short* __restrict__ owbf, const float* __restrict__ obias,
    float* __restrict__ out){
  int mbase = blockIdx.x*128;
  int tid = threadIdx.x, w = tid>>6, l = tid&63;
  int lr = l&15, lk = (l>>4)*8;
  __shared__ unsigned short at[128*40];
  __shared__ float osh[128][129];
  f32x4 acc[8][2];
  #pragma unroll
  for (int m=0;m<8;m++){ acc[m][0] = (f32x4){0,0,0,0}; acc[m][1] = (f32x4){0,0,0,0}; }
  for (int kt=0; kt<32; ++kt){
    int row = tid>>1, half = (tid&1)*16;
    const unsigned short* sp = ybf + (size_t)(mbase+row)*1024 + kt*32 + half;
    *(float4*)&at[row*40 + half]     = *(const float4*)sp;
    *(float4*)&at[row*40 + half + 8] = *(const float4*)(sp + 8);
    __syncthreads();
    bf16x8 b0 = *(const bf16x8*)(owbf + ((2*w+0)*16 + lr)*1024 + kt*32 + lk);
    bf16x8 b1 = *(const bf16x8*)(owbf + ((2*w+1)*16 + lr)*1024 + kt*32 + lk);
    #pragma unroll
    for (int m=0;m<8;m++){
      bf16x8 afrag = *(const bf16x8*)&at[(m*16+lr)*40 + lk];
      acc[m][0] = __builtin_amdgcn_mfma_f32_16x16x32_bf16(afrag, b0, acc[m][0], 0,0,0);
      acc[m][1] = __builtin_amdgcn_mfma_f32_16x16x32_bf16(afrag, b1, acc[m][1], 0,0,0);
    }
    __syncthreads();
  }
  #pragma unroll
  for (int m=0;m<8;m++){
    #pragma unroll
    for (int j=0;j<2;j++){
      int o = (2*w+j)*16 + lr;
      float ob = obias[o];
      #pragma unroll
      for (int i=0;i<4;i++){
        int r = m*16 + (l>>4)*4 + i;
        osh[r][o] = acc[m][j][i] + ob;
      }
    }
  }
  __syncthreads();
  if (tid < 128){
    const float* row = osh[tid];
    int r = mbase + tid;
    float mx = -1e30f;
    #pragma unroll
    for (int k2=0;k2<20;k2++) mx = fmaxf(mx, row[k2]);
    float e[20]; float s = 0;
    #pragma unroll
    for (int k2=0;k2<20;k2++){ e[k2] = __expf(row[k2]-mx); s += e[k2]; }
    float inv = __builtin_amdgcn_rcpf(s);
    float* mixo  = out;
    float* meano = out + 163840;
    float* scaleo= out + 491520;
    float* corro = out + 819200;
    float* vlogo = out + 983040;
    #pragma unroll
    for (int k2=0;k2<20;k2++) mixo[r*20+k2] = e[k2]*inv;
    #pragma unroll
    for (int j=0;j<40;j++) meano[r*40+j] = row[20+j];
    #pragma unroll
    for (int j=0;j<40;j++) scaleo[r*40+j] = __expf(row[60+j]);
    #pragma unroll
    for (int k2=0;k2<20;k2++) corro[r*20+k2] = ftanh(row[100+k2]);
    vlogo[r] = row[120];
  }
}

extern "C" void kernel_launch(void* const* d_in, const int* in_sizes, int n_in,
                              void* d_out, int out_size, void* d_ws, size_t ws_size,
                              hipStream_t stream){
  const float* x       = (const float*)d_in[0];
  const float* x_canv  = (const float*)d_in[1];
  const float* start_  = (const float*)d_in[2];
  const float* conv1_w = (const float*)d_in[3];
  const float* conv1_b = (const float*)d_in[4];
  const float* conv2_w = (const float*)d_in[5];
  const float* conv2_b = (const float*)d_in[6];
  const float* conv3_w = (const float*)d_in[7];
  const float* conv3_b = (const float*)d_in[8];
  const float* init_w  = (const float*)d_in[9];
  const float* init_b  = (const float*)d_in[10];
  const float* Uw      = (const float*)d_in[11];
  const float* Ub      = (const float*)d_in[12];
  const float* Ww      = (const float*)d_in[13];
  const float* Wb      = (const float*)d_in[14];
  const float* vw      = (const float*)d_in[15];
  const float* vb      = (const float*)d_in[16];
  const float* beta_w  = (const float*)d_in[17];
  const float* beta_b  = (const float*)d_in[18];
  const float* xemb_w  = (const float*)d_in[19];
  const float* xemb_b  = (const float*)d_in[20];
  const float* semb_w  = (const float*)d_in[21];
  const float* semb_b  = (const float*)d_in[22];
  const float* Wih     = (const float*)d_in[23];
  const float* Whh     = (const float*)d_in[24];
  const float* bih     = (const float*)d_in[25];
  const float* bhh     = (const float*)d_in[26];
  const float* comb_w  = (const float*)d_in[27];
  const float* comb_b  = (const float*)d_in[28];
  const float* out_w   = (const float*)d_in[29];
  const float* out_b   = (const float*)d_in[30];
  (void)in_sizes; (void)n_in; (void)out_size; (void)ws_size;

  char* wsb = (char*)d_ws;
  size_t off = 0;
  auto alloc = [&](size_t bytes)->char*{
    char* p = wsb + off;
    off = (off + bytes + 255) & ~(size_t)255;
    return p;
  };
  unsigned short* c1bf   = (unsigned short*)alloc((size_t)TN*16*784*2);
  unsigned short* a2     = (unsigned short*)alloc((size_t)100352*160*2);  // a3 aliases a2
  unsigned short* a3     = a2;
  unsigned short* c2bf   = (unsigned short*)alloc((size_t)100352*32*2);
  unsigned short* afbf   = (unsigned short*)alloc((size_t)TN*64*196*2);
  unsigned short* abf    = (unsigned short*)alloc((size_t)TN*196*64*2);
  unsigned short* wabf   = (unsigned short*)alloc((size_t)TN*196*128*2);
  float*          cbuf   = (float*)alloc((size_t)TN*512*4);
  unsigned short* hbfA   = (unsigned short*)alloc((size_t)TN*512*2);
  unsigned short* hbfB   = (unsigned short*)alloc((size_t)TN*512*2);
  unsigned short* ubf_all= (unsigned short*)alloc((size_t)TT*TN*96*2);
  unsigned short* cbf    = (unsigned short*)alloc((size_t)TN*TT*608*2);
  unsigned short* ybf    = (unsigned short*)alloc((size_t)TN*TT*1024*2);
  unsigned short* wgf    = (unsigned short*)alloc((size_t)1245184*2);
  float*          gbias  = (float*)alloc((size_t)2048*4);
  float*          gpart  = (float*)alloc((size_t)4*128*512*4);
  unsigned short* cwbf   = (unsigned short*)alloc((size_t)1024*608*2);
  unsigned short* owbf   = (unsigned short*)alloc((size_t)128*1024*2);
  float*          obias  = (float*)alloc((size_t)128*4);
  unsigned short* uwbf   = (unsigned short*)alloc((size_t)128*512*2);
  unsigned short* betabf = (unsigned short*)alloc((size_t)64*512*2);
  unsigned short* wwbf   = (unsigned short*)alloc((size_t)128*64*2);
  unsigned short* w2b    = (unsigned short*)alloc((size_t)32*160*2);
  unsigned short* w3b    = (unsigned short*)alloc((size_t)64*320*2);

  hipLaunchKernelGGL(k_head, dim3(7314), dim3(256), 0, stream,
                     x_canv, conv1_w, conv1_b, c1bf,
                     Whh, Wih, bih, bhh, comb_w, out_w, out_b, Uw, beta_w, Ww, conv2_w, conv3_w,
                     wgf, gbias, cwbf, owbf, obias, uwbf, betabf, wwbf, w2b, w3b);
  hipLaunchKernelGGL(k_im2col2, dim3(7840), dim3(256), 0, stream, c1bf, a2);
  hipLaunchKernelGGL(k_gconv2, dim3(784), dim3(256), 0, stream, a2, w2b, conv2_b, c2bf);
  hipLaunchKernelGGL(k_im2col3, dim3(3920), dim3(256), 0, stream, c2bf, a3);
  hipLaunchKernelGGL(k_gconv3, dim3(196), dim3(256), 0, stream, a3, w3b, conv3_b, afbf, abf);
  hipLaunchKernelGGL(k_mid, dim3(2372), dim3(256), 0, stream,
                     afbf, start_, semb_w, semb_b,
                     abf, wwbf, Wb, wabf,
                     x, xemb_w, xemb_b, cbf, ubf_all,
                     init_w, init_b, hbfA, cbuf);

  for (int t = 0; t < TT; ++t){
    unsigned short* hin  = (t & 1) ? hbfB : hbfA;
    unsigned short* hout = (t & 1) ? hbfA : hbfB;
    hipLaunchKernelGGL(k_stepA, dim3(160), dim3(512), 0, stream, t,
                       hin, uwbf, Ub, betabf, beta_b, vw, vb, wabf, afbf, ubf_all, cbf, wgf, gpart);
    hipLaunchKernelGGL(k_stepB, dim3(32), dim3(512), 0, stream, t,
                       hout, ubf_all, wgf, gbias, gpart, cbuf, cbf);
  }

  hipLaunchKernelGGL(k_comb, dim3(64, 8), dim3(256), 0, stream, cbf, cwbf, comb_b, ybf);
  hipLaunchKernelGGL(k_out, dim3(64), dim3(256), 0, stream, ybf, owbf, obias, (float*)d_out);
}